// Round 5
// baseline (276.732 us; speedup 1.0000x reference)
//
#include <hip/hip_runtime.h>
#include <hip/hip_bf16.h>
#include <math.h>

#define BB 8
#define NN 2048
#define DD 128
#define LL 3
#define GN_EPS 1e-5f

typedef __attribute__((ext_vector_type(8))) short bf16x8;
typedef __attribute__((ext_vector_type(4))) float f32x4;
typedef __attribute__((ext_vector_type(8))) unsigned short u16x8;

// round-half-up f32 -> bf16 bits
__device__ __forceinline__ unsigned short f2bf(float f) {
    union { float f; unsigned u; } v; v.f = f;
    return (unsigned short)((v.u + 0x8000u) >> 16);
}

__device__ __forceinline__ float fast_tanh(float x) {
    float e = __expf(-2.0f * fabsf(x));
    float t = (1.0f - e) * __builtin_amdgcn_rcpf(1.0f + e);
    return copysignf(t, x);
}

// GraphNorm affine fold: h_norm = s*h + c
__device__ __forceinline__ void stats_sc(float ps, float pq, float a, float w_,
                                         float b_, float& s, float& c) {
    const float inv_n = 1.0f / (float)NN;
    float mean = ps * inv_n;
    float msq  = pq * inv_n;
    float var  = msq - mean * mean * a * (2.0f - a);
    float rstd = rsqrtf(var + GN_EPS);
    s = w_ * rstd;
    c = b_ - s * (a * mean);
}

// ---------------------------------------------------------------------------
// K0: prep_wg — pack Wg (3x128x128 f32) into bf16 MFMA A-frag order.
// ---------------------------------------------------------------------------
__global__ __launch_bounds__(256)
void prep_wg(const float* __restrict__ Wg, unsigned short* __restrict__ wgf)
{
    const int f = blockIdx.x * 256 + threadIdx.x;    // < 3*128*128
    const int l  = f >> 14;
    const int r  = f & 16383;
    const int dp = r >> 7;
    const int e  = r & 127;
    const int dpt = dp >> 4, ll = dp & 15;
    const int kc  = e >> 5,  eo = e & 31;
    wgf[((((l * 8 + dpt) * 4 + kc) * 16 + ll) << 5) + eo] = f2bf(Wg[f]);
}

// ---------------------------------------------------------------------------
// K1: gen_adj — A[b][n][m] = dist(n,m) + I (bf16), dinv = rsqrt(rowsum).
// ---------------------------------------------------------------------------
__global__ __launch_bounds__(256)
void gen_adj(const float* __restrict__ inst, unsigned short* __restrict__ A,
             float* __restrict__ dinv)
{
    __shared__ float cs[NN * 2];
    const int b   = blockIdx.x >> 6;
    const int n0  = (blockIdx.x & 63) * 32;
    const int tid = threadIdx.x;
    const int w    = tid >> 6;
    const int lane = tid & 63;

    const float* instb = inst + b * NN * 2;
    for (int i = tid; i < (NN * 2) / 4; i += 256)
        ((float4*)cs)[i] = ((const float4*)instb)[i];
    __syncthreads();

    float mx[4][8], my[4][8];
    #pragma unroll
    for (int c = 0; c < 4; ++c)
        #pragma unroll
        for (int e = 0; e < 8; ++e) {
            int m = c * 512 + lane * 8 + e;
            mx[c][e] = cs[m * 2 + 0];
            my[c][e] = cs[m * 2 + 1];
        }

    for (int r = 0; r < 8; ++r) {
        const int n = n0 + w * 8 + r;
        const float nxv = cs[n * 2 + 0];
        const float nyv = cs[n * 2 + 1];
        float rs = 0.f;
        unsigned short* Arow = A + ((size_t)b * NN + n) * NN;
        #pragma unroll
        for (int c = 0; c < 4; ++c) {
            const int mb = c * 512 + lane * 8;
            u16x8 pk;
            #pragma unroll
            for (int e = 0; e < 8; ++e) {
                float dx = nxv - mx[c][e];
                float dy = nyv - my[c][e];
                float dist = sqrtf(dx * dx + dy * dy);
                if (mb + e == n) dist = 1.0f;          // self-loop
                rs += dist;
                pk[e] = f2bf(dist);
            }
            *(u16x8*)(Arow + mb) = pk;
        }
        #pragma unroll
        for (int off = 1; off < 64; off <<= 1) rs += __shfl_xor(rs, off);
        if (lane == 0) dinv[b * NN + n] = rsqrtf(rs);
    }
}

// ---------------------------------------------------------------------------
// K2: proj_node + zero all per-layer stats buffers
// ---------------------------------------------------------------------------
__global__ __launch_bounds__(256)
void proj_kernel(const float* __restrict__ inst, const float* __restrict__ Wn,
                 const float* __restrict__ bn, float* __restrict__ h,
                 float* __restrict__ psum, float* __restrict__ psq)
{
    const int idx = blockIdx.x * 256 + threadIdx.x;
    const int d   = idx & (DD - 1);
    const int row = idx >> 7;
    const float x0 = inst[row * 2 + 0];
    const float x1 = inst[row * 2 + 1];
    h[idx] = x0 * Wn[d * 2 + 0] + x1 * Wn[d * 2 + 1] + bn[d];
    if (blockIdx.x == 0) {
        for (int i = threadIdx.x; i < LL * BB * DD; i += 256) {
            psum[i] = 0.0f; psq[i] = 0.0f;
        }
    }
}

// ---------------------------------------------------------------------------
// K3: lin (MFMA). tT[b][d'][m] = bf16( dinv[m] * sum_e norm(h)[m][e]*Wg[d'][e] )
// norm via previous layer stats computed in an LDS prologue (identity if !HP).
// Block 32 nodes, grid 512. Wave w: d'-tiles {2w,2w+1}.
// ---------------------------------------------------------------------------
template <bool HP>
__global__ __launch_bounds__(256)
void lin_mfma(const float* __restrict__ h, const unsigned short* __restrict__ wgf_l,
              const float* __restrict__ dinv,
              const float* __restrict__ psumP, const float* __restrict__ psqP,
              const float* __restrict__ ga, const float* __restrict__ gw,
              const float* __restrict__ gb, unsigned short* __restrict__ tT)
{
    __shared__ float sL[DD], cL[DD];
    const int tid  = threadIdx.x;
    const int row0 = blockIdx.x * 32;
    const int b    = row0 >> 11;
    const int w    = tid >> 6;
    const int lane = tid & 63;
    const int lq   = lane >> 4;
    const int ll   = lane & 15;

    if (tid < DD) {
        float s = 1.0f, c = 0.0f;
        if (HP)
            stats_sc(psumP[b * DD + tid], psqP[b * DD + tid],
                     ga[tid], gw[tid], gb[tid], s, c);
        sL[tid] = s; cL[tid] = c;
    }
    __syncthreads();

    // Wg A-frags
    bf16x8 aw[2][4];
    #pragma unroll
    for (int mt = 0; mt < 2; ++mt) {
        const int dpt = 2 * w + mt;
        #pragma unroll
        for (int kc = 0; kc < 4; ++kc)
            aw[mt][kc] = *(const bf16x8*)&wgf_l[(((dpt * 4 + kc) * 16 + ll) << 5) + lq * 8];
    }

    // h B-frags with norm applied
    bf16x8 bh[2][4];
    #pragma unroll
    for (int nt = 0; nt < 2; ++nt) {
        const float* hrow = h + (size_t)(row0 + nt * 16 + ll) * DD;
        #pragma unroll
        for (int kc = 0; kc < 4; ++kc) {
            float4 h0 = *(const float4*)&hrow[kc * 32 + lq * 8];
            float4 h1 = *(const float4*)&hrow[kc * 32 + lq * 8 + 4];
            const int e0 = kc * 32 + lq * 8;
            bf16x8 p;
            p[0] = (short)f2bf(fmaf(sL[e0 + 0], h0.x, cL[e0 + 0]));
            p[1] = (short)f2bf(fmaf(sL[e0 + 1], h0.y, cL[e0 + 1]));
            p[2] = (short)f2bf(fmaf(sL[e0 + 2], h0.z, cL[e0 + 2]));
            p[3] = (short)f2bf(fmaf(sL[e0 + 3], h0.w, cL[e0 + 3]));
            p[4] = (short)f2bf(fmaf(sL[e0 + 4], h1.x, cL[e0 + 4]));
            p[5] = (short)f2bf(fmaf(sL[e0 + 5], h1.y, cL[e0 + 5]));
            p[6] = (short)f2bf(fmaf(sL[e0 + 6], h1.z, cL[e0 + 6]));
            p[7] = (short)f2bf(fmaf(sL[e0 + 7], h1.w, cL[e0 + 7]));
            bh[nt][kc] = p;
        }
    }

    f32x4 acc[2][2];   // [mt][nt]
    #pragma unroll
    for (int i = 0; i < 2; ++i)
        #pragma unroll
        for (int j = 0; j < 2; ++j) acc[i][j] = (f32x4)0.0f;

    #pragma unroll
    for (int kc = 0; kc < 4; ++kc)
        #pragma unroll
        for (int mt = 0; mt < 2; ++mt)
            #pragma unroll
            for (int nt = 0; nt < 2; ++nt)
                acc[mt][nt] = __builtin_amdgcn_mfma_f32_16x16x32_bf16(
                    aw[mt][kc], bh[nt][kc], acc[mt][nt], 0, 0, 0);

    // store tT transposed with dinv folded
    const int nbase = row0 & (NN - 1);
    #pragma unroll
    for (int nt = 0; nt < 2; ++nt) {
        const int nloc = nbase + nt * 16 + ll;
        const float di = dinv[row0 + nt * 16 + ll];
        #pragma unroll
        for (int mt = 0; mt < 2; ++mt) {
            #pragma unroll
            for (int reg = 0; reg < 4; ++reg) {
                int dp = (2 * w + mt) * 16 + lq * 4 + reg;
                tT[((size_t)(b * DD + dp)) * NN + nloc] = f2bf(acc[mt][nt][reg] * di);
            }
        }
    }
}

// ---------------------------------------------------------------------------
// K4: agg — barrier-free K-split MFMA GEMM + fused epilogue.
// C[n][d] = sum_m A[n][m]*t[m][d].  Block 32n x 64d, grid 1024 (4/CU),
// blockIdx = [dh(1)][b(3)][ntile(6)] so dh-partners share an XCD.
// Wave w owns K-range [w*512,(w+1)*512): 16 chunks x (6 loads + 8 MFMA),
// 2-deep register pipeline pinned by sched_group_barrier (VMEMx6, MFMAx8).
// Cross-wave reduce via 32KB LDS, then tanh+residual+stats epilogue.
// ---------------------------------------------------------------------------
template <bool HP>
__global__ __launch_bounds__(256, 4)
void agg_mfma(const unsigned short* __restrict__ A, const unsigned short* __restrict__ tT,
              const float* __restrict__ dinv, const float* __restrict__ bg_l,
              const float* __restrict__ psumP, const float* __restrict__ psqP,
              const float* __restrict__ ga, const float* __restrict__ gw,
              const float* __restrict__ gb,
              float* __restrict__ h, float* __restrict__ psum, float* __restrict__ psq)
{
    __shared__ f32x4 red[4][8][64];   // 32 KB
    const int b   = (blockIdx.x >> 6) & 7;
    const int n0  = (blockIdx.x & 63) * 32;
    const int d0  = (blockIdx.x >> 9) * 64;
    const int tid = threadIdx.x;
    const int w    = tid >> 6;
    const int lane = tid & 63;
    const int lq   = lane >> 4;
    const int ll   = lane & 15;

    const unsigned short* Ab = A + ((size_t)b * NN + n0) * NN + w * 512 + lq * 8;
    const unsigned short* ga0 = Ab + (size_t)ll * NN;         // nt=0
    const unsigned short* ga1 = Ab + (size_t)(16 + ll) * NN;  // nt=1
    const unsigned short* tb = tT + (size_t)b * DD * NN + w * 512 + lq * 8;
    const unsigned short* gbp[4];
    #pragma unroll
    for (int dt = 0; dt < 4; ++dt)
        gbp[dt] = tb + (size_t)(d0 + dt * 16 + ll) * NN;

    f32x4 acc[2][4];   // [nt][dt]
    #pragma unroll
    for (int i = 0; i < 2; ++i)
        #pragma unroll
        for (int j = 0; j < 4; ++j) acc[i][j] = (f32x4)0.0f;

    bf16x8 fa[2][2], fb[2][4];

    // prologue load chunk 0
    fa[0][0] = *(const bf16x8*)(ga0);
    fa[0][1] = *(const bf16x8*)(ga1);
    #pragma unroll
    for (int dt = 0; dt < 4; ++dt) fb[0][dt] = *(const bf16x8*)(gbp[dt]);

    #pragma unroll
    for (int k = 0; k < 16; ++k) {
        if (k < 15) {
            const int buf = (k + 1) & 1;
            const int mo  = (k + 1) * 32;
            fa[buf][0] = *(const bf16x8*)(ga0 + mo);
            fa[buf][1] = *(const bf16x8*)(ga1 + mo);
            #pragma unroll
            for (int dt = 0; dt < 4; ++dt)
                fb[buf][dt] = *(const bf16x8*)(gbp[dt] + mo);
            __builtin_amdgcn_sched_group_barrier(0x020, 6, 0);  // 6 VMEM reads
        }
        const int buf = k & 1;
        #pragma unroll
        for (int dt = 0; dt < 4; ++dt)
            #pragma unroll
            for (int nt = 0; nt < 2; ++nt)
                acc[nt][dt] = __builtin_amdgcn_mfma_f32_16x16x32_bf16(
                    fa[buf][nt], fb[buf][dt], acc[nt][dt], 0, 0, 0);
        __builtin_amdgcn_sched_group_barrier(0x008, 8, 0);      // 8 MFMA
    }

    // ---- cross-wave reduction
    #pragma unroll
    for (int nt = 0; nt < 2; ++nt)
        #pragma unroll
        for (int dt = 0; dt < 4; ++dt)
            red[w][nt * 4 + dt][lane] = acc[nt][dt];
    __syncthreads();

    // wave w handles frags {w, w+4}: dt = w, both n-halves -> one d per lane
    const int d = d0 + w * 16 + ll;
    float sres = 1.0f, cres = 0.0f;
    if (HP)
        stats_sc(psumP[b * DD + d], psqP[b * DD + d], ga[d], gw[d], gb[d], sres, cres);
    const float bgv = bg_l[d];
    float hs = 0.f, hq = 0.f;
    #pragma unroll
    for (int half = 0; half < 2; ++half) {
        const int f = half * 4 + w;
        f32x4 v = red[0][f][lane];
        v += red[1][f][lane];
        v += red[2][f][lane];
        v += red[3][f][lane];
        #pragma unroll
        for (int r = 0; r < 4; ++r) {
            const int n = n0 + half * 16 + lq * 4 + r;
            const float di = dinv[b * NN + n];
            size_t idx = ((size_t)b * NN + n) * DD + d;
            float pre = di * v[r] + bgv;
            float outv = fast_tanh(pre) + fmaf(sres, h[idx], cres);
            h[idx] = outv;
            hs += outv;
            hq += outv * outv;
        }
    }
    hs += __shfl_xor(hs, 16); hs += __shfl_xor(hs, 32);
    hq += __shfl_xor(hq, 16); hq += __shfl_xor(hq, 32);
    if (lq == 0) {
        atomicAdd(&psum[b * DD + d], hs);
        atomicAdd(&psq[b * DD + d], hq);
    }
}

// ---------------------------------------------------------------------------
// K5: final apply with in-thread stats from layer-2 buffers
// ---------------------------------------------------------------------------
__global__ __launch_bounds__(256)
void apply_kernel(const float* __restrict__ h,
                  const float* __restrict__ psum2, const float* __restrict__ psq2,
                  const float* __restrict__ ga, const float* __restrict__ gw,
                  const float* __restrict__ gb, float* __restrict__ dst)
{
    const int i4 = blockIdx.x * 256 + threadIdx.x;    // < B*N*D/4
    const int dg = (i4 & 31) * 4;
    const int b  = i4 >> 16;                          // N*D/4 = 65536
    float4 hv = ((const float4*)h)[i4];
    float o[4];
    #pragma unroll
    for (int j = 0; j < 4; ++j) {
        const int d = dg + j;
        float s, c;
        stats_sc(psum2[b * DD + d], psq2[b * DD + d], ga[d], gw[d], gb[d], s, c);
        o[j] = fmaf(s, (&hv.x)[j], c);
    }
    float4 ov = { o[0], o[1], o[2], o[3] };
    ((float4*)dst)[i4] = ov;
}

// ---------------------------------------------------------------------------
extern "C" void kernel_launch(void* const* d_in, const int* in_sizes, int n_in,
                              void* d_out, int out_size, void* d_ws, size_t ws_size,
                              hipStream_t stream)
{
    const float* inst = (const float*)d_in[0];
    const float* Wn   = (const float*)d_in[1];
    const float* bn   = (const float*)d_in[2];
    const float* Wg   = (const float*)d_in[3];
    const float* bg   = (const float*)d_in[4];
    const float* gw   = (const float*)d_in[5];
    const float* gb   = (const float*)d_in[6];
    const float* ga   = (const float*)d_in[7];
    float* out = (float*)d_out;

    float* ws   = (float*)d_ws;
    float* dinv = ws;                                   // B*N
    float* h    = dinv + BB * NN;                       // B*N*D
    float* psum = h + (size_t)BB * NN * DD;             // LL*B*D
    float* psq  = psum + LL * BB * DD;                  // LL*B*D
    unsigned short* wgf = (unsigned short*)(psq + LL * BB * DD);  // LL*D*D bf16
    unsigned short* tT  = wgf + LL * DD * DD;                     // B*D*N bf16 (4MB)
    unsigned short* A   = tT + (size_t)BB * DD * NN;              // B*N*N bf16 (64MB)

    prep_wg<<<(LL * DD * DD) / 256, 256, 0, stream>>>(Wg, wgf);
    gen_adj<<<BB * 64, 256, 0, stream>>>(inst, A, dinv);
    proj_kernel<<<(BB * NN * DD) / 256, 256, 0, stream>>>(inst, Wn, bn, h, psum, psq);

    for (int l = 0; l < LL; ++l) {
        const unsigned short* wgl = wgf + (size_t)l * DD * DD;
        const float* psP = psum + (size_t)(l - 1) * BB * DD;
        const float* pqP = psq  + (size_t)(l - 1) * BB * DD;
        float* psL = psum + (size_t)l * BB * DD;
        float* pqL = psq  + (size_t)l * BB * DD;
        if (l == 0) {
            lin_mfma<false><<<(BB * NN) / 32, 256, 0, stream>>>(
                h, wgl, dinv, nullptr, nullptr, ga, gw, gb, tT);
            agg_mfma<false><<<BB * 64 * 2, 256, 0, stream>>>(
                A, tT, dinv, bg + l * DD, nullptr, nullptr, ga, gw, gb, h, psL, pqL);
        } else {
            lin_mfma<true><<<(BB * NN) / 32, 256, 0, stream>>>(
                h, wgl, dinv, psP, pqP, ga, gw, gb, tT);
            agg_mfma<true><<<BB * 64 * 2, 256, 0, stream>>>(
                A, tT, dinv, bg + l * DD, psP, pqP, ga, gw, gb, h, psL, pqL);
        }
    }
    apply_kernel<<<(BB * NN * DD / 4) / 256, 256, 0, stream>>>(
        h, psum + 2 * BB * DD, psq + 2 * BB * DD, ga, gw, gb, out);
}

// Round 6
// 258.320 us; speedup vs baseline: 1.0713x; 1.0713x over previous
//
#include <hip/hip_runtime.h>
#include <hip/hip_bf16.h>
#include <math.h>

#define BB 8
#define NN 2048
#define DD 128
#define LL 3
#define GN_EPS 1e-5f

typedef __attribute__((ext_vector_type(8))) short bf16x8;
typedef __attribute__((ext_vector_type(4))) float f32x4;

// round-half-up f32 -> bf16 bits
__device__ __forceinline__ unsigned short f2bf(float f) {
    union { float f; unsigned u; } v; v.f = f;
    return (unsigned short)((v.u + 0x8000u) >> 16);
}

__device__ __forceinline__ float bf2f(unsigned short s) {
    union { unsigned u; float f; } v; v.u = ((unsigned)s) << 16;
    return v.f;
}

__device__ __forceinline__ float fast_tanh(float x) {
    float e = __expf(-2.0f * fabsf(x));
    float t = (1.0f - e) * __builtin_amdgcn_rcpf(1.0f + e);
    return copysignf(t, x);
}

// GraphNorm affine fold: h_norm = s*h + c
__device__ __forceinline__ void stats_sc(float ps, float pq, float a, float w_,
                                         float b_, float& s, float& c) {
    const float inv_n = 1.0f / (float)NN;
    float mean = ps * inv_n;
    float msq  = pq * inv_n;
    float var  = msq - mean * mean * a * (2.0f - a);
    float rstd = rsqrtf(var + GN_EPS);
    s = w_ * rstd;
    c = b_ - s * (a * mean);
}

// ---------------------------------------------------------------------------
// K0: prep_wg — pack Wg (3x128x128 f32) into bf16 MFMA A-frag order.
// ---------------------------------------------------------------------------
__global__ __launch_bounds__(256)
void prep_wg(const float* __restrict__ Wg, unsigned short* __restrict__ wgf)
{
    const int f = blockIdx.x * 256 + threadIdx.x;    // < 3*128*128
    const int l  = f >> 14;
    const int r  = f & 16383;
    const int dp = r >> 7;
    const int e  = r & 127;
    const int dpt = dp >> 4, ll = dp & 15;
    const int kc  = e >> 5,  eo = e & 31;
    wgf[((((l * 8 + dpt) * 4 + kc) * 16 + ll) << 5) + eo] = f2bf(Wg[f]);
}

// ---------------------------------------------------------------------------
// K1: deg — dinv[b][n] = rsqrt( sum_m dist(n,m) + 1 ).  No A store.
// grid 512 (b x 64 tiles of 32 rows), 4 waves, wave owns 8 rows.
// ---------------------------------------------------------------------------
__global__ __launch_bounds__(256)
void deg_kernel(const float* __restrict__ inst, float* __restrict__ dinv)
{
    __shared__ float cs[NN * 2];
    const int b   = blockIdx.x >> 6;
    const int n0  = (blockIdx.x & 63) * 32;
    const int tid = threadIdx.x;
    const int w    = tid >> 6;
    const int lane = tid & 63;

    const float* instb = inst + b * NN * 2;
    for (int i = tid; i < (NN * 2) / 4; i += 256)
        ((float4*)cs)[i] = ((const float4*)instb)[i];
    __syncthreads();

    float mx[4][8], my[4][8];
    #pragma unroll
    for (int c = 0; c < 4; ++c)
        #pragma unroll
        for (int e = 0; e < 8; ++e) {
            int m = c * 512 + lane * 8 + e;
            mx[c][e] = cs[m * 2 + 0];
            my[c][e] = cs[m * 2 + 1];
        }

    for (int r = 0; r < 8; ++r) {
        const int n = n0 + w * 8 + r;
        const float nxv = cs[n * 2 + 0];
        const float nyv = cs[n * 2 + 1];
        float rs = 0.f;
        #pragma unroll
        for (int c = 0; c < 4; ++c)
            #pragma unroll
            for (int e = 0; e < 8; ++e) {
                float dx = nxv - mx[c][e];
                float dy = nyv - my[c][e];
                rs += sqrtf(dx * dx + dy * dy);   // diag contributes 0
            }
        #pragma unroll
        for (int off = 1; off < 64; off <<= 1) rs += __shfl_xor(rs, off);
        if (lane == 0) dinv[b * NN + n] = rsqrtf(rs + 1.0f);
    }
}

// ---------------------------------------------------------------------------
// K2: proj_node + zero all per-layer stats buffers
// ---------------------------------------------------------------------------
__global__ __launch_bounds__(256)
void proj_kernel(const float* __restrict__ inst, const float* __restrict__ Wn,
                 const float* __restrict__ bn, float* __restrict__ h,
                 float* __restrict__ psum, float* __restrict__ psq)
{
    const int idx = blockIdx.x * 256 + threadIdx.x;
    const int d   = idx & (DD - 1);
    const int row = idx >> 7;
    const float x0 = inst[row * 2 + 0];
    const float x1 = inst[row * 2 + 1];
    h[idx] = x0 * Wn[d * 2 + 0] + x1 * Wn[d * 2 + 1] + bn[d];
    if (blockIdx.x == 0) {
        for (int i = threadIdx.x; i < LL * BB * DD; i += 256) {
            psum[i] = 0.0f; psq[i] = 0.0f;
        }
    }
}

// ---------------------------------------------------------------------------
// K3: lin (MFMA). tT[b][d'][m] = bf16( dinv[m] * sum_e norm(h)[m][e]*Wg[d'][e] )
// ---------------------------------------------------------------------------
template <bool HP>
__global__ __launch_bounds__(256)
void lin_mfma(const float* __restrict__ h, const unsigned short* __restrict__ wgf_l,
              const float* __restrict__ dinv,
              const float* __restrict__ psumP, const float* __restrict__ psqP,
              const float* __restrict__ ga, const float* __restrict__ gw,
              const float* __restrict__ gb, unsigned short* __restrict__ tT)
{
    __shared__ float sL[DD], cL[DD];
    const int tid  = threadIdx.x;
    const int row0 = blockIdx.x * 32;
    const int b    = row0 >> 11;
    const int w    = tid >> 6;
    const int lane = tid & 63;
    const int lq   = lane >> 4;
    const int ll   = lane & 15;

    if (tid < DD) {
        float s = 1.0f, c = 0.0f;
        if (HP)
            stats_sc(psumP[b * DD + tid], psqP[b * DD + tid],
                     ga[tid], gw[tid], gb[tid], s, c);
        sL[tid] = s; cL[tid] = c;
    }
    __syncthreads();

    bf16x8 aw[2][4];
    #pragma unroll
    for (int mt = 0; mt < 2; ++mt) {
        const int dpt = 2 * w + mt;
        #pragma unroll
        for (int kc = 0; kc < 4; ++kc)
            aw[mt][kc] = *(const bf16x8*)&wgf_l[(((dpt * 4 + kc) * 16 + ll) << 5) + lq * 8];
    }

    bf16x8 bh[2][4];
    #pragma unroll
    for (int nt = 0; nt < 2; ++nt) {
        const float* hrow = h + (size_t)(row0 + nt * 16 + ll) * DD;
        #pragma unroll
        for (int kc = 0; kc < 4; ++kc) {
            float4 h0 = *(const float4*)&hrow[kc * 32 + lq * 8];
            float4 h1 = *(const float4*)&hrow[kc * 32 + lq * 8 + 4];
            const int e0 = kc * 32 + lq * 8;
            bf16x8 p;
            p[0] = (short)f2bf(fmaf(sL[e0 + 0], h0.x, cL[e0 + 0]));
            p[1] = (short)f2bf(fmaf(sL[e0 + 1], h0.y, cL[e0 + 1]));
            p[2] = (short)f2bf(fmaf(sL[e0 + 2], h0.z, cL[e0 + 2]));
            p[3] = (short)f2bf(fmaf(sL[e0 + 3], h0.w, cL[e0 + 3]));
            p[4] = (short)f2bf(fmaf(sL[e0 + 4], h1.x, cL[e0 + 4]));
            p[5] = (short)f2bf(fmaf(sL[e0 + 5], h1.y, cL[e0 + 5]));
            p[6] = (short)f2bf(fmaf(sL[e0 + 6], h1.z, cL[e0 + 6]));
            p[7] = (short)f2bf(fmaf(sL[e0 + 7], h1.w, cL[e0 + 7]));
            bh[nt][kc] = p;
        }
    }

    f32x4 acc[2][2];   // [mt][nt]
    #pragma unroll
    for (int i = 0; i < 2; ++i)
        #pragma unroll
        for (int j = 0; j < 2; ++j) acc[i][j] = (f32x4)0.0f;

    #pragma unroll
    for (int kc = 0; kc < 4; ++kc)
        #pragma unroll
        for (int mt = 0; mt < 2; ++mt)
            #pragma unroll
            for (int nt = 0; nt < 2; ++nt)
                acc[mt][nt] = __builtin_amdgcn_mfma_f32_16x16x32_bf16(
                    aw[mt][kc], bh[nt][kc], acc[mt][nt], 0, 0, 0);

    const int nbase = row0 & (NN - 1);
    #pragma unroll
    for (int nt = 0; nt < 2; ++nt) {
        const int nloc = nbase + nt * 16 + ll;
        const float di = dinv[row0 + nt * 16 + ll];
        #pragma unroll
        for (int mt = 0; mt < 2; ++mt) {
            #pragma unroll
            for (int reg = 0; reg < 4; ++reg) {
                int dp = (2 * w + mt) * 16 + lq * 4 + reg;
                tT[((size_t)(b * DD + dp)) * NN + nloc] = f2bf(acc[mt][nt][reg] * di);
            }
        }
    }
}

// ---------------------------------------------------------------------------
// K4: agg — A regenerated in registers, no A memory traffic at all.
// C[n][d] = sum_m dist(n,m)*t[m][d]; self-loop added in epilogue.
// Block 64n x 128d, grid 256 = [ntile(5b)][b(3b)] so batch b -> XCD b
// (tT slice 512KB stays L2-resident).  4 waves, wave w owns K-range
// [w*512,(w+1)*512): 16 chunks of 32 m.  Per chunk: 4 LDS coord reads,
// 32 dist computations (~450 VALU cyc, covers B-load L2 latency), 8 B-loads,
// 32 MFMAs.  Barrier-free K-loop; 2-round LDS reduction; fused epilogue.
// ---------------------------------------------------------------------------
template <bool HP>
__global__ __launch_bounds__(256, 1)
void agg_mfma(const float* __restrict__ inst, const unsigned short* __restrict__ tT,
              const float* __restrict__ dinv, const float* __restrict__ bg_l,
              const float* __restrict__ psumP, const float* __restrict__ psqP,
              const float* __restrict__ ga, const float* __restrict__ gw,
              const float* __restrict__ gb,
              float* __restrict__ h, float* __restrict__ psum, float* __restrict__ psq)
{
    __shared__ float cs[NN * 2];          // 16 KB coords
    __shared__ f32x4 red[4][16][64];      // 64 KB reduction buffer
    const int b    = blockIdx.x & 7;
    const int n0   = (blockIdx.x >> 3) * 64;
    const int tid  = threadIdx.x;
    const int w    = tid >> 6;
    const int lane = tid & 63;
    const int lq   = lane >> 4;
    const int ll   = lane & 15;

    const float* instb = inst + b * NN * 2;
    for (int i = tid; i < (NN * 2) / 4; i += 256)
        ((float4*)cs)[i] = ((const float4*)instb)[i];
    __syncthreads();

    // n-coords for this lane's 4 A-frag rows
    float nx[4], ny[4];
    #pragma unroll
    for (int nt = 0; nt < 4; ++nt) {
        int n = n0 + nt * 16 + ll;
        nx[nt] = cs[n * 2 + 0];
        ny[nt] = cs[n * 2 + 1];
    }

    // B pointers: tT d-rows, this wave's K-range
    const unsigned short* tTb = tT + (size_t)b * DD * NN + w * 512 + lq * 8;
    const unsigned short* gbp[8];
    #pragma unroll
    for (int dt = 0; dt < 8; ++dt)
        gbp[dt] = tTb + (size_t)(dt * 16 + ll) * NN;

    f32x4 acc[4][8];   // [nt][dt]
    #pragma unroll
    for (int i = 0; i < 4; ++i)
        #pragma unroll
        for (int j = 0; j < 8; ++j) acc[i][j] = (f32x4)0.0f;

    const int mwbase = w * 512 + lq * 8;

    #pragma unroll 2
    for (int kc = 0; kc < 16; ++kc) {
        const int mo = kc * 32;
        // B-frags for this chunk (issued first; A-gen below covers latency)
        bf16x8 fb[8];
        #pragma unroll
        for (int dt = 0; dt < 8; ++dt)
            fb[dt] = *(const bf16x8*)(gbp[dt] + mo);

        // m-coords from LDS: 8 m's = 4 x b128
        const float* cp = &cs[(mwbase + mo) * 2];
        float4 c01 = *(const float4*)(cp + 0);
        float4 c23 = *(const float4*)(cp + 4);
        float4 c45 = *(const float4*)(cp + 8);
        float4 c67 = *(const float4*)(cp + 12);
        float mx[8] = { c01.x, c01.z, c23.x, c23.z, c45.x, c45.z, c67.x, c67.z };
        float my[8] = { c01.y, c01.w, c23.y, c23.w, c45.y, c45.w, c67.y, c67.w };

        // A-frags: dist(n,m); diag naturally 0, self-loop added in epilogue
        bf16x8 af[4];
        #pragma unroll
        for (int nt = 0; nt < 4; ++nt) {
            float dist[8];
            #pragma unroll
            for (int j = 0; j < 8; ++j) {
                float dx = nx[nt] - mx[j];
                float dy = ny[nt] - my[j];
                dist[j] = sqrtf(dx * dx + dy * dy);
            }
            union { bf16x8 v; __hip_bfloat162 h2[4]; } u;
            #pragma unroll
            for (int p = 0; p < 4; ++p)
                u.h2[p] = __float22bfloat162_rn(make_float2(dist[2 * p], dist[2 * p + 1]));
            af[nt] = u.v;
        }

        #pragma unroll
        for (int dt = 0; dt < 8; ++dt)
            #pragma unroll
            for (int nt = 0; nt < 4; ++nt)
                acc[nt][dt] = __builtin_amdgcn_mfma_f32_16x16x32_bf16(
                    af[nt], fb[dt], acc[nt][dt], 0, 0, 0);
    }

    // ---- cross-wave reduction + epilogue, two rounds (nt 0..1, then 2..3)
    const unsigned short* tTself = tT + (size_t)b * DD * NN;
    __syncthreads();
    #pragma unroll
    for (int round = 0; round < 2; ++round) {
        #pragma unroll
        for (int f = 0; f < 16; ++f)
            red[w][f][lane] = acc[(f >> 3) + round * 2][f & 7];
        __syncthreads();

        #pragma unroll
        for (int i = 0; i < 4; ++i) {
            const int f  = w * 4 + i;
            const int nt = (f >> 3) + round * 2;
            const int dt = f & 7;
            f32x4 v = red[0][f][lane];
            v += red[1][f][lane];
            v += red[2][f][lane];
            v += red[3][f][lane];
            const int d = dt * 16 + ll;
            float sres = 1.0f, cres = 0.0f;
            if (HP)
                stats_sc(psumP[b * DD + d], psqP[b * DD + d],
                         ga[d], gw[d], gb[d], sres, cres);
            const float bgv = bg_l[d];
            float hs = 0.f, hq = 0.f;
            #pragma unroll
            for (int r = 0; r < 4; ++r) {
                const int n = n0 + nt * 16 + lq * 4 + r;
                const float di = dinv[b * NN + n];
                const float tself = bf2f(tTself[(size_t)d * NN + n]);
                size_t idx = ((size_t)b * NN + n) * DD + d;
                float pre = di * (v[r] + tself) + bgv;
                float outv = fast_tanh(pre) + fmaf(sres, h[idx], cres);
                h[idx] = outv;
                hs += outv;
                hq += outv * outv;
            }
            hs += __shfl_xor(hs, 16); hs += __shfl_xor(hs, 32);
            hq += __shfl_xor(hq, 16); hq += __shfl_xor(hq, 32);
            if (lq == 0) {
                atomicAdd(&psum[b * DD + d], hs);
                atomicAdd(&psq[b * DD + d], hq);
            }
        }
        __syncthreads();
    }
}

// ---------------------------------------------------------------------------
// K5: final apply with in-thread stats from layer-2 buffers
// ---------------------------------------------------------------------------
__global__ __launch_bounds__(256)
void apply_kernel(const float* __restrict__ h,
                  const float* __restrict__ psum2, const float* __restrict__ psq2,
                  const float* __restrict__ ga, const float* __restrict__ gw,
                  const float* __restrict__ gb, float* __restrict__ dst)
{
    const int i4 = blockIdx.x * 256 + threadIdx.x;    // < B*N*D/4
    const int dg = (i4 & 31) * 4;
    const int b  = i4 >> 16;                          // N*D/4 = 65536
    float4 hv = ((const float4*)h)[i4];
    float o[4];
    #pragma unroll
    for (int j = 0; j < 4; ++j) {
        const int d = dg + j;
        float s, c;
        stats_sc(psum2[b * DD + d], psq2[b * DD + d], ga[d], gw[d], gb[d], s, c);
        o[j] = fmaf(s, (&hv.x)[j], c);
    }
    float4 ov = { o[0], o[1], o[2], o[3] };
    ((float4*)dst)[i4] = ov;
}

// ---------------------------------------------------------------------------
extern "C" void kernel_launch(void* const* d_in, const int* in_sizes, int n_in,
                              void* d_out, int out_size, void* d_ws, size_t ws_size,
                              hipStream_t stream)
{
    const float* inst = (const float*)d_in[0];
    const float* Wn   = (const float*)d_in[1];
    const float* bn   = (const float*)d_in[2];
    const float* Wg   = (const float*)d_in[3];
    const float* bg   = (const float*)d_in[4];
    const float* gw   = (const float*)d_in[5];
    const float* gb   = (const float*)d_in[6];
    const float* ga   = (const float*)d_in[7];
    float* out = (float*)d_out;

    float* ws   = (float*)d_ws;
    float* dinv = ws;                                   // B*N
    float* h    = dinv + BB * NN;                       // B*N*D
    float* psum = h + (size_t)BB * NN * DD;             // LL*B*D
    float* psq  = psum + LL * BB * DD;                  // LL*B*D
    unsigned short* wgf = (unsigned short*)(psq + LL * BB * DD);  // LL*D*D bf16
    unsigned short* tT  = wgf + LL * DD * DD;                     // B*D*N bf16 (8MB)

    prep_wg<<<(LL * DD * DD) / 256, 256, 0, stream>>>(Wg, wgf);
    deg_kernel<<<BB * 64, 256, 0, stream>>>(inst, dinv);
    proj_kernel<<<(BB * NN * DD) / 256, 256, 0, stream>>>(inst, Wn, bn, h, psum, psq);

    for (int l = 0; l < LL; ++l) {
        const unsigned short* wgl = wgf + (size_t)l * DD * DD;
        const float* psP = psum + (size_t)(l - 1) * BB * DD;
        const float* pqP = psq  + (size_t)(l - 1) * BB * DD;
        float* psL = psum + (size_t)l * BB * DD;
        float* pqL = psq  + (size_t)l * BB * DD;
        if (l == 0) {
            lin_mfma<false><<<(BB * NN) / 32, 256, 0, stream>>>(
                h, wgl, dinv, nullptr, nullptr, ga, gw, gb, tT);
            agg_mfma<false><<<(NN / 64) * BB, 256, 0, stream>>>(
                inst, tT, dinv, bg + l * DD, nullptr, nullptr, ga, gw, gb, h, psL, pqL);
        } else {
            lin_mfma<true><<<(BB * NN) / 32, 256, 0, stream>>>(
                h, wgl, dinv, psP, pqP, ga, gw, gb, tT);
            agg_mfma<true><<<(NN / 64) * BB, 256, 0, stream>>>(
                inst, tT, dinv, bg + l * DD, psP, pqP, ga, gw, gb, h, psL, pqL);
        }
    }
    apply_kernel<<<(BB * NN * DD / 4) / 256, 256, 0, stream>>>(
        h, psum + 2 * BB * DD, psq + 2 * BB * DD, ga, gw, gb, out);
}